// Round 11
// baseline (284.073 us; speedup 1.0000x reference)
//
#include <hip/hip_runtime.h>
#include <hip/hip_fp16.h>
#include <cstddef>

#define NEG_SLOPE 0.2f
#define TILE 4096
#define CSR_CAP 6144   // fixed per-bucket capacity; mean ~4096, sigma ~64

typedef _Float16 h8 __attribute__((ext_vector_type(8)));
typedef _Float16 h4 __attribute__((ext_vector_type(4)));
typedef float f4 __attribute__((ext_vector_type(4)));

__device__ __forceinline__ float leaky(float x) { return x >= 0.f ? x : NEG_SLOPE * x; }

__device__ __forceinline__ int wave_iscan(int v, int lane) {
#pragma unroll
    for (int off = 1; off < 64; off <<= 1) {
        int t = __shfl_up(v, off);
        if (lane >= off) v += t;
    }
    return v;
}

// ---------------------------------------------------------------------------
// MFMA GEMM + fused alpha dots (layer 1). h = x @ W1, hh = fp16(h).
// ---------------------------------------------------------------------------
template <int F>
__global__ __launch_bounds__(256) void gemm_mfma(
    const float* __restrict__ x, const float* __restrict__ W,
    const float* __restrict__ a_s, const float* __restrict__ a_d,
    _Float16* __restrict__ hh, float* __restrict__ alphaS, float* __restrict__ alphaD,
    int N)
{
    constexpr int K = 128;
    constexpr int LDK = K + 8;
    constexpr int NT = F / 16;

    __shared__ _Float16 As[64 * LDK];
    __shared__ _Float16 Wt[F * LDK];

    const int tid = threadIdx.x;
    const int wave = tid >> 6;
    const int lane = tid & 63;
    const int q = lane >> 4;
    const int c = lane & 15;
    const int rowb = blockIdx.x * 64;

    for (int i = tid; i < 64 * (K / 4); i += 256) {
        int r = i >> 5, c4 = i & 31;
        int gr = rowb + r;
        float4 v = (gr < N) ? *(const float4*)(x + (size_t)gr * K + c4 * 4)
                            : make_float4(0.f, 0.f, 0.f, 0.f);
        h4 hv = { (_Float16)v.x, (_Float16)v.y, (_Float16)v.z, (_Float16)v.w };
        *(h4*)(As + r * LDK + c4 * 4) = hv;
    }
    for (int i = tid; i < K * F; i += 256) {
        int k = i / F, n = i % F;
        Wt[n * LDK + k] = (_Float16)W[i];
    }
    __syncthreads();

    f4 acc[NT];
#pragma unroll
    for (int nt = 0; nt < NT; nt++) acc[nt] = (f4)0.f;

    const _Float16* aw = As + (wave * 16 + c) * LDK + q * 8;
#pragma unroll
    for (int kt = 0; kt < 4; kt++) {
        h8 af = *(const h8*)(aw + kt * 32);
#pragma unroll
        for (int nt = 0; nt < NT; nt++) {
            h8 bf = *(const h8*)(Wt + (nt * 16 + c) * LDK + kt * 32 + q * 8);
            acc[nt] = __builtin_amdgcn_mfma_f32_16x16x32_f16(af, bf, acc[nt], 0, 0, 0);
        }
    }

    float asl[NT], adl[NT];
#pragma unroll
    for (int nt = 0; nt < NT; nt++) {
        asl[nt] = a_s[nt * 16 + c];
        adl[nt] = a_d[nt * 16 + c];
    }
    const int row0 = rowb + wave * 16 + q * 4;
#pragma unroll
    for (int r = 0; r < 4; r++) {
        int row = row0 + r;
        if (row < N) {
            float ps = 0.f, pd = 0.f;
#pragma unroll
            for (int nt = 0; nt < NT; nt++) {
                float v = acc[nt][r];
                hh[(size_t)row * F + nt * 16 + c] = (_Float16)v;
                ps += v * asl[nt];
                pd += v * adl[nt];
            }
#pragma unroll
            for (int off = 8; off >= 1; off >>= 1) {
                ps += __shfl_down(ps, off, 16);
                pd += __shfl_down(pd, off, 16);
            }
            if (c == 0) { alphaS[row] = ps; alphaD[row] = pd; }
        }
    }
}

// ---------------------------------------------------------------------------
// CSR build, 2 kernels. Fixed-cap per-bucket staging regions (stride cap),
// bfill[] zeroed by memset. Packed u32 pair = (dst<<16)|src (N < 65536).
// ---------------------------------------------------------------------------
__global__ __launch_bounds__(256) void bucket_scatter(
    const int* __restrict__ src, const int* __restrict__ dst,
    int* __restrict__ bfill, unsigned* __restrict__ staging, int cap, int E)
{
    __shared__ int lcnt[256];
    __shared__ int loff[256];
    __shared__ int gbase[256];
    __shared__ int ws[4];
    __shared__ unsigned pairs[TILE];
    __shared__ unsigned char bkt[TILE];

    const int tid = threadIdx.x;
    const int base = blockIdx.x * TILE;
    const int vt = min(TILE, E - base);

    lcnt[tid] = 0;
    __syncthreads();

    int d[TILE / 256], s[TILE / 256], r[TILE / 256];
#pragma unroll
    for (int j = 0; j < TILE / 256; j++) {
        int idx = base + j * 256 + tid;
        if (idx < E) {
            d[j] = dst[idx]; s[j] = src[idx];
            r[j] = atomicAdd(&lcnt[d[j] >> 8], 1);
        } else d[j] = -1;
    }
    __syncthreads();
    {
        int lane = tid & 63, wid = tid >> 6;
        int v = lcnt[tid];
        int incl = wave_iscan(v, lane);
        if (lane == 63) ws[wid] = incl;
        __syncthreads();
        int woff = 0;
        for (int w = 0; w < wid; w++) woff += ws[w];
        loff[tid] = woff + incl - v;
    }
    __syncthreads();
    {
        int c = lcnt[tid];
        if (c > 0) gbase[tid] = tid * cap + atomicAdd(&bfill[tid], c);
    }
    __syncthreads();
#pragma unroll
    for (int j = 0; j < TILE / 256; j++) {
        if (d[j] >= 0) {
            int b = d[j] >> 8;
            int slot = loff[b] + r[j];
            pairs[slot] = ((unsigned)d[j] << 16) | (unsigned)s[j];
            bkt[slot] = (unsigned char)b;
        }
    }
    __syncthreads();
    for (int slot = tid; slot < vt; slot += 256) {
        int b = bkt[slot];
        staging[gbase[b] + (slot - loff[b])] = pairs[slot];
    }
}

__global__ __launch_bounds__(256) void bucket_to_csr(
    const unsigned* __restrict__ staging, const int* __restrict__ bfill,
    int* __restrict__ row_start, int* __restrict__ row_end,
    int* __restrict__ src_sorted, int cap, int N)
{
    __shared__ unsigned lp[CSR_CAP];
    __shared__ int lcnt[256], loff[256], lfill[256];
    __shared__ int ws[4];
    const int tid = threadIdx.x;
    const int b = blockIdx.x;
    const int beg = b * cap;
    const int len = bfill[b];

    lcnt[tid] = 0;
    __syncthreads();
    for (int p = tid; p < len; p += 256) {
        unsigned u = staging[beg + p];
        if (p < CSR_CAP) lp[p] = u;
        atomicAdd(&lcnt[(u >> 16) & 255], 1);
    }
    __syncthreads();
    {
        int lane = tid & 63, wid = tid >> 6;
        int v = lcnt[tid];
        int incl = wave_iscan(v, lane);
        if (lane == 63) ws[wid] = incl;
        __syncthreads();
        int woff = 0;
        for (int w = 0; w < wid; w++) woff += ws[w];
        int excl = woff + incl - v;
        loff[tid] = excl;
        lfill[tid] = excl;
        int node = (b << 8) + tid;
        if (node < N) { row_start[node] = beg + excl; row_end[node] = beg + excl + v; }
    }
    __syncthreads();
    for (int p = tid; p < len; p += 256) {
        unsigned u = (p < CSR_CAP) ? lp[p] : staging[beg + p];
        int pos = atomicAdd(&lfill[(u >> 16) & 255], 1);
        src_sorted[beg + pos] = (int)(u & 0xFFFFu);
    }
}

// ---------------------------------------------------------------------------
// Layer-1 aggregate FUSED with layer-2 GEMM + alpha2.
// Per wave: gather-aggregate one node's x2 row (lanes 0-15 hold 8 feats each,
// bias+ReLU applied), then h2 = x2 @ W2 via shfl-broadcast (lane n computes
// column n of h2 from LDS-resident fp16 W2), alpha2 by wave reduction.
// Grid-stride over nodes so W2 is staged once per block.
// ---------------------------------------------------------------------------
__global__ __launch_bounds__(256) void gat_agg_fused(
    const int* __restrict__ row_start, const int* __restrict__ row_end,
    const int* __restrict__ src_sorted, const __half* __restrict__ hh,
    const float* __restrict__ aS, const float* __restrict__ aD,
    const float* __restrict__ bias, const float* __restrict__ W2,
    const float* __restrict__ aS2, const float* __restrict__ aD2,
    _Float16* __restrict__ hh2, float* __restrict__ alphaS2, float* __restrict__ alphaD2,
    int N)
{
    constexpr int F = 128;
    constexpr int LPE = F / 8;          // 16 lanes per edge
    constexpr int EPW = 64 / LPE;       // 4 edge slots per wave

    __shared__ _Float16 w2s[128 * 64];
    const int tid = threadIdx.x;
    for (int i = tid; i < 128 * 64; i += 256) w2s[i] = (_Float16)W2[i];
    __syncthreads();

    const int wave = tid >> 6;
    const int lane = tid & 63;
    const int sub = lane / LPE;
    const int l = lane % LPE;
    const float a2s = aS2[lane], a2d = aD2[lane];

    for (int i = blockIdx.x * 4 + wave; i < N; i += gridDim.x * 4) {
        const float adi = aD[i];
        const int start = row_start[i];
        const int end = row_end[i];

        float accA[8], accB[8];
#pragma unroll
        for (int q = 0; q < 8; q++) { accA[q] = 0.f; accB[q] = 0.f; }
        float denA = 0.f, denB = 0.f;

        int e = start + sub;
        int s0 = (e + 0 * EPW < end) ? src_sorted[e + 0 * EPW] : -1;
        int s1 = (e + 1 * EPW < end) ? src_sorted[e + 1 * EPW] : -1;
        int s2 = (e + 2 * EPW < end) ? src_sorted[e + 2 * EPW] : -1;
        int s3 = (e + 3 * EPW < end) ? src_sorted[e + 3 * EPW] : -1;

        while (s0 >= 0) {
            int eb = e + 4 * EPW;
            int n0 = (eb + 0 * EPW < end) ? src_sorted[eb + 0 * EPW] : -1;
            int n1 = (eb + 1 * EPW < end) ? src_sorted[eb + 1 * EPW] : -1;
            int n2 = (eb + 2 * EPW < end) ? src_sorted[eb + 2 * EPW] : -1;
            int n3 = (eb + 3 * EPW < end) ? src_sorted[eb + 3 * EPW] : -1;
            {
                float w = __expf(leaky(aS[s0] + adi));
                uint4 u = *(const uint4*)(hh + (size_t)s0 * F + l * 8);
                const __half2* hp = (const __half2*)&u;
#pragma unroll
                for (int q = 0; q < 4; q++) {
                    float2 f = __half22float2(hp[q]);
                    accA[q * 2] += w * f.x; accA[q * 2 + 1] += w * f.y;
                }
                denA += w;
            }
            if (s1 >= 0) {
                float w = __expf(leaky(aS[s1] + adi));
                uint4 u = *(const uint4*)(hh + (size_t)s1 * F + l * 8);
                const __half2* hp = (const __half2*)&u;
#pragma unroll
                for (int q = 0; q < 4; q++) {
                    float2 f = __half22float2(hp[q]);
                    accB[q * 2] += w * f.x; accB[q * 2 + 1] += w * f.y;
                }
                denB += w;
            }
            if (s2 >= 0) {
                float w = __expf(leaky(aS[s2] + adi));
                uint4 u = *(const uint4*)(hh + (size_t)s2 * F + l * 8);
                const __half2* hp = (const __half2*)&u;
#pragma unroll
                for (int q = 0; q < 4; q++) {
                    float2 f = __half22float2(hp[q]);
                    accA[q * 2] += w * f.x; accA[q * 2 + 1] += w * f.y;
                }
                denA += w;
            }
            if (s3 >= 0) {
                float w = __expf(leaky(aS[s3] + adi));
                uint4 u = *(const uint4*)(hh + (size_t)s3 * F + l * 8);
                const __half2* hp = (const __half2*)&u;
#pragma unroll
                for (int q = 0; q < 4; q++) {
                    float2 f = __half22float2(hp[q]);
                    accB[q * 2] += w * f.x; accB[q * 2 + 1] += w * f.y;
                }
                denB += w;
            }
            e = eb;
            s0 = n0; s1 = n1; s2 = n2; s3 = n3;
        }

        float acc[8];
#pragma unroll
        for (int q = 0; q < 8; q++) acc[q] = accA[q] + accB[q];
        float denom = denA + denB;

#pragma unroll
        for (int off = 32; off >= LPE; off >>= 1) {
#pragma unroll
            for (int q = 0; q < 8; q++) acc[q] += __shfl_down(acc[q], off);
            denom += __shfl_down(denom, off);
        }

        // x2 row (valid on lanes 0-15; feature k = l*8+q): bias + ReLU
        float o[8];
        {
            float wsf = __expf(leaky(aS[i] + adi));
            uint4 u = *(const uint4*)(hh + (size_t)i * F + l * 8);
            const __half2* hp = (const __half2*)&u;
            float inv = 1.f / (denom + wsf);
            float4 b0 = *(const float4*)(bias + l * 8);
            float4 b1 = *(const float4*)(bias + l * 8 + 4);
#pragma unroll
            for (int q = 0; q < 4; q++) {
                float2 f = __half22float2(hp[q]);
                o[q * 2]     = (acc[q * 2]     + wsf * f.x) * inv;
                o[q * 2 + 1] = (acc[q * 2 + 1] + wsf * f.y) * inv;
            }
            o[0] += b0.x; o[1] += b0.y; o[2] += b0.z; o[3] += b0.w;
            o[4] += b1.x; o[5] += b1.y; o[6] += b1.z; o[7] += b1.w;
#pragma unroll
            for (int q = 0; q < 8; q++) o[q] = fmaxf(o[q], 0.f);
        }

        // h2[n] = sum_k x2[k] * W2[k][n]; lane `lane` computes column n=lane.
        float h2v = 0.f;
#pragma unroll
        for (int q = 0; q < 8; q++) {
#pragma unroll
            for (int l16 = 0; l16 < 16; l16++) {
                float xv = __shfl(o[q], l16);
                h2v += xv * (float)w2s[(l16 * 8 + q) * 64 + lane];
            }
        }
        hh2[(size_t)i * 64 + lane] = (_Float16)h2v;

        float ps = h2v * a2s, pd = h2v * a2d;
#pragma unroll
        for (int off = 32; off >= 1; off >>= 1) {
            ps += __shfl_down(ps, off);
            pd += __shfl_down(pd, off);
        }
        if (lane == 0) { alphaS2[i] = ps; alphaD2[i] = pd; }
    }
}

// ---------------------------------------------------------------------------
// Layer-2 aggregate (final): fp16 gather 16 B/lane, writes fp32 d_out.
// ---------------------------------------------------------------------------
template <int F>
__global__ __launch_bounds__(256) void gat_aggregate2(
    const int* __restrict__ row_start, const int* __restrict__ row_end,
    const int* __restrict__ src_sorted, const __half* __restrict__ hh,
    const float* __restrict__ aS, const float* __restrict__ aD,
    const float* __restrict__ bias, float* __restrict__ out, int N)
{
    constexpr int LPE = F / 8;          // 8 lanes per edge (F=64)
    constexpr int EPW = 64 / LPE;       // 8 edge slots per wave

    const int i = blockIdx.x * 4 + (threadIdx.x >> 6);
    if (i >= N) return;
    const int lane = threadIdx.x & 63;
    const int sub = lane / LPE;
    const int l = lane % LPE;

    const float adi = aD[i];
    const int start = row_start[i];
    const int end = row_end[i];

    float acc0[8], acc1[8];
#pragma unroll
    for (int q = 0; q < 8; q++) { acc0[q] = 0.f; acc1[q] = 0.f; }
    float den0 = 0.f, den1 = 0.f;

    int e0 = start + sub;
    int e1 = e0 + EPW;
    int s0 = (e0 < end) ? src_sorted[e0] : -1;
    int s1 = (e1 < end) ? src_sorted[e1] : -1;

    while (s0 >= 0) {
        int n0 = (e0 + 2 * EPW < end) ? src_sorted[e0 + 2 * EPW] : -1;
        int n1 = (e1 + 2 * EPW < end) ? src_sorted[e1 + 2 * EPW] : -1;
        {
            float w = __expf(leaky(aS[s0] + adi));
            uint4 u = *(const uint4*)(hh + (size_t)s0 * F + l * 8);
            const __half2* hp = (const __half2*)&u;
#pragma unroll
            for (int q = 0; q < 4; q++) {
                float2 f = __half22float2(hp[q]);
                acc0[q * 2] += w * f.x; acc0[q * 2 + 1] += w * f.y;
            }
            den0 += w;
        }
        if (s1 >= 0) {
            float w = __expf(leaky(aS[s1] + adi));
            uint4 u = *(const uint4*)(hh + (size_t)s1 * F + l * 8);
            const __half2* hp = (const __half2*)&u;
#pragma unroll
            for (int q = 0; q < 4; q++) {
                float2 f = __half22float2(hp[q]);
                acc1[q * 2] += w * f.x; acc1[q * 2 + 1] += w * f.y;
            }
            den1 += w;
        }
        e0 += 2 * EPW; e1 += 2 * EPW;
        s0 = n0; s1 = n1;
    }

    float acc[8];
#pragma unroll
    for (int q = 0; q < 8; q++) acc[q] = acc0[q] + acc1[q];
    float denom = den0 + den1;

#pragma unroll
    for (int off = 32; off >= LPE; off >>= 1) {
#pragma unroll
        for (int q = 0; q < 8; q++) acc[q] += __shfl_down(acc[q], off);
        denom += __shfl_down(denom, off);
    }

    if (sub == 0) {
        float wsf = __expf(leaky(aS[i] + adi));
        uint4 u = *(const uint4*)(hh + (size_t)i * F + l * 8);
        const __half2* hp = (const __half2*)&u;
        float inv = 1.f / (denom + wsf);
        float4 b0 = *(const float4*)(bias + l * 8);
        float4 b1 = *(const float4*)(bias + l * 8 + 4);
        float o[8];
#pragma unroll
        for (int q = 0; q < 4; q++) {
            float2 f = __half22float2(hp[q]);
            o[q * 2]     = (acc[q * 2]     + wsf * f.x) * inv;
            o[q * 2 + 1] = (acc[q * 2 + 1] + wsf * f.y) * inv;
        }
        o[0] += b0.x; o[1] += b0.y; o[2] += b0.z; o[3] += b0.w;
        o[4] += b1.x; o[5] += b1.y; o[6] += b1.z; o[7] += b1.w;
        *(float4*)(out + (size_t)i * F + l * 8)     = make_float4(o[0], o[1], o[2], o[3]);
        *(float4*)(out + (size_t)i * F + l * 8 + 4) = make_float4(o[4], o[5], o[6], o[7]);
    }
}

extern "C" void kernel_launch(void* const* d_in, const int* in_sizes, int n_in,
                              void* d_out, int out_size, void* d_ws, size_t ws_size,
                              hipStream_t stream)
{
    const float* x   = (const float*)d_in[0];
    const int*   ei  = (const int*)d_in[1];
    const float* W1  = (const float*)d_in[2];
    const float* aS1 = (const float*)d_in[3];
    const float* aD1 = (const float*)d_in[4];
    const float* b1  = (const float*)d_in[5];
    const float* W2  = (const float*)d_in[6];
    const float* aS2 = (const float*)d_in[7];
    const float* aD2 = (const float*)d_in[8];
    const float* b2  = (const float*)d_in[9];

    const int K = 128, F1 = 128, F2 = 64;
    const int N = in_sizes[0] / K;   // 50000 (< 65536: packed u32 staging valid)
    const int E = in_sizes[1] / 2;
    const int* src = ei;
    const int* dst = ei + E;

    const int Np = (N + 4) & ~3;
    const int NB = (N + 255) >> 8;
    const int nbt = (E + TILE - 1) / TILE;
    int cap = (((E / NB) * 3) / 2 + 255) & ~255;   // 1.5x mean, 256-aligned
    if (cap > CSR_CAP) cap = CSR_CAP;

    char* wsb = (char*)d_ws;
    int* bfill        = (int*)wsb;      wsb += 256 * 4;                       // zeroed
    int* row_start    = (int*)wsb;      wsb += (size_t)Np * 4;
    int* row_end      = (int*)wsb;      wsb += (size_t)Np * 4;
    unsigned* staging = (unsigned*)wsb; wsb += (size_t)NB * CSR_CAP * 4;
    int* src_sorted   = (int*)wsb;      wsb += (size_t)NB * CSR_CAP * 4;
    _Float16* hh1     = (_Float16*)wsb; wsb += (size_t)N * F1 * 2;
    _Float16* hh2     = (_Float16*)wsb; wsb += (size_t)N * F2 * 2;
    float* as_        = (float*)wsb;    wsb += (size_t)Np * 4;
    float* ad_        = (float*)wsb;    wsb += (size_t)Np * 4;
    float* as2_       = (float*)wsb;    wsb += (size_t)Np * 4;
    float* ad2_       = (float*)wsb;    wsb += (size_t)Np * 4;

    hipMemsetAsync(bfill, 0, 256 * 4, stream);

    dim3 blk(256);

    // ---- layer-1 GEMM (MFMA) ----
    gemm_mfma<F1><<<dim3((N + 63) / 64), blk, 0, stream>>>(
        x, W1, aS1, aD1, hh1, as_, ad_, N);

    // ---- CSR build (2 kernels, fixed-cap buckets) ----
    bucket_scatter<<<dim3(nbt), blk, 0, stream>>>(src, dst, bfill, staging, cap, E);
    bucket_to_csr<<<dim3(NB), blk, 0, stream>>>(staging, bfill, row_start, row_end,
                                                src_sorted, cap, N);

    // ---- layer-1 aggregate fused with layer-2 GEMM + alpha2 ----
    gat_agg_fused<<<dim3(2048), blk, 0, stream>>>(
        row_start, row_end, src_sorted, (const __half*)hh1, as_, ad_, b1,
        W2, aS2, aD2, hh2, as2_, ad2_, N);

    // ---- layer-2 aggregate -> d_out ----
    gat_aggregate2<F2><<<dim3((N + 3) / 4), blk, 0, stream>>>(
        row_start, row_end, src_sorted, (const __half*)hh2, as2_, ad2_, b2,
        (float*)d_out, N);
}

// Round 12
// 199.735 us; speedup vs baseline: 1.4223x; 1.4223x over previous
//
#include <hip/hip_runtime.h>
#include <hip/hip_fp16.h>
#include <cstddef>

#define NEG_SLOPE 0.2f
#define TILE 4096
#define CSR_CAP 6144   // fixed per-bucket capacity; mean ~4096, sigma ~64

typedef _Float16 h8 __attribute__((ext_vector_type(8)));
typedef _Float16 h4 __attribute__((ext_vector_type(4)));
typedef float f4 __attribute__((ext_vector_type(4)));

__device__ __forceinline__ float leaky(float x) { return x >= 0.f ? x : NEG_SLOPE * x; }

__device__ __forceinline__ int wave_iscan(int v, int lane) {
#pragma unroll
    for (int off = 1; off < 64; off <<= 1) {
        int t = __shfl_up(v, off);
        if (lane >= off) v += t;
    }
    return v;
}

// ---------------------------------------------------------------------------
// MFMA GEMM + fused alpha dots. h = x @ W (x: [N,128], W: [128,F] fp32 rm),
// hh = fp16(h). K=128 staged entirely in LDS (fp16).
// ---------------------------------------------------------------------------
template <int F, typename IT>
__global__ __launch_bounds__(256) void gemm_mfma(
    const IT* __restrict__ x, const float* __restrict__ W,
    const float* __restrict__ a_s, const float* __restrict__ a_d,
    _Float16* __restrict__ hh, float* __restrict__ alphaS, float* __restrict__ alphaD,
    int N)
{
    constexpr int K = 128;
    constexpr int LDK = K + 8;
    constexpr int NT = F / 16;

    __shared__ _Float16 As[64 * LDK];
    __shared__ _Float16 Wt[F * LDK];

    const int tid = threadIdx.x;
    const int wave = tid >> 6;
    const int lane = tid & 63;
    const int q = lane >> 4;
    const int c = lane & 15;
    const int rowb = blockIdx.x * 64;

    if constexpr (sizeof(IT) == 4) {
        for (int i = tid; i < 64 * (K / 4); i += 256) {
            int r = i >> 5, c4 = i & 31;
            int gr = rowb + r;
            float4 v = (gr < N) ? *(const float4*)((const float*)x + (size_t)gr * K + c4 * 4)
                                : make_float4(0.f, 0.f, 0.f, 0.f);
            h4 hv = { (_Float16)v.x, (_Float16)v.y, (_Float16)v.z, (_Float16)v.w };
            *(h4*)(As + r * LDK + c4 * 4) = hv;
        }
    } else {
        for (int i = tid; i < 64 * (K / 8); i += 256) {
            int r = i >> 4, c8 = i & 15;
            int gr = rowb + r;
            h8 v;
            if (gr < N) v = *(const h8*)((const _Float16*)x + (size_t)gr * K + c8 * 8);
            else        v = (h8)(_Float16)0.f;
            *(h8*)(As + r * LDK + c8 * 8) = v;
        }
    }
    for (int i = tid; i < K * F; i += 256) {
        int k = i / F, n = i % F;
        Wt[n * LDK + k] = (_Float16)W[i];
    }
    __syncthreads();

    f4 acc[NT];
#pragma unroll
    for (int nt = 0; nt < NT; nt++) acc[nt] = (f4)0.f;

    const _Float16* aw = As + (wave * 16 + c) * LDK + q * 8;
#pragma unroll
    for (int kt = 0; kt < 4; kt++) {
        h8 af = *(const h8*)(aw + kt * 32);
#pragma unroll
        for (int nt = 0; nt < NT; nt++) {
            h8 bf = *(const h8*)(Wt + (nt * 16 + c) * LDK + kt * 32 + q * 8);
            acc[nt] = __builtin_amdgcn_mfma_f32_16x16x32_f16(af, bf, acc[nt], 0, 0, 0);
        }
    }

    float asl[NT], adl[NT];
#pragma unroll
    for (int nt = 0; nt < NT; nt++) {
        asl[nt] = a_s[nt * 16 + c];
        adl[nt] = a_d[nt * 16 + c];
    }
    const int row0 = rowb + wave * 16 + q * 4;
#pragma unroll
    for (int r = 0; r < 4; r++) {
        int row = row0 + r;
        if (row < N) {
            float ps = 0.f, pd = 0.f;
#pragma unroll
            for (int nt = 0; nt < NT; nt++) {
                float v = acc[nt][r];
                hh[(size_t)row * F + nt * 16 + c] = (_Float16)v;
                ps += v * asl[nt];
                pd += v * adl[nt];
            }
#pragma unroll
            for (int off = 8; off >= 1; off >>= 1) {
                ps += __shfl_down(ps, off, 16);
                pd += __shfl_down(pd, off, 16);
            }
            if (c == 0) { alphaS[row] = ps; alphaD[row] = pd; }
        }
    }
}

// ---------------------------------------------------------------------------
// CSR build, 2 kernels. Fixed-cap per-bucket staging regions (stride cap),
// bfill[] zeroed by memset. Packed u32 pair = (dst<<16)|src (N < 65536).
// Gapped CSR: per-node [row_start, row_end).
// ---------------------------------------------------------------------------
__global__ __launch_bounds__(256) void bucket_scatter(
    const int* __restrict__ src, const int* __restrict__ dst,
    int* __restrict__ bfill, unsigned* __restrict__ staging, int cap, int E)
{
    __shared__ int lcnt[256];
    __shared__ int loff[256];
    __shared__ int gbase[256];
    __shared__ int ws[4];
    __shared__ unsigned pairs[TILE];
    __shared__ unsigned char bkt[TILE];

    const int tid = threadIdx.x;
    const int base = blockIdx.x * TILE;
    const int vt = min(TILE, E - base);

    lcnt[tid] = 0;
    __syncthreads();

    int d[TILE / 256], s[TILE / 256], r[TILE / 256];
#pragma unroll
    for (int j = 0; j < TILE / 256; j++) {
        int idx = base + j * 256 + tid;
        if (idx < E) {
            d[j] = dst[idx]; s[j] = src[idx];
            r[j] = atomicAdd(&lcnt[d[j] >> 8], 1);
        } else d[j] = -1;
    }
    __syncthreads();
    {
        int lane = tid & 63, wid = tid >> 6;
        int v = lcnt[tid];
        int incl = wave_iscan(v, lane);
        if (lane == 63) ws[wid] = incl;
        __syncthreads();
        int woff = 0;
        for (int w = 0; w < wid; w++) woff += ws[w];
        loff[tid] = woff + incl - v;
    }
    __syncthreads();
    {
        int c = lcnt[tid];
        if (c > 0) gbase[tid] = tid * cap + atomicAdd(&bfill[tid], c);
    }
    __syncthreads();
#pragma unroll
    for (int j = 0; j < TILE / 256; j++) {
        if (d[j] >= 0) {
            int b = d[j] >> 8;
            int slot = loff[b] + r[j];
            pairs[slot] = ((unsigned)d[j] << 16) | (unsigned)s[j];
            bkt[slot] = (unsigned char)b;
        }
    }
    __syncthreads();
    for (int slot = tid; slot < vt; slot += 256) {
        int b = bkt[slot];
        staging[gbase[b] + (slot - loff[b])] = pairs[slot];
    }
}

__global__ __launch_bounds__(256) void bucket_to_csr(
    const unsigned* __restrict__ staging, const int* __restrict__ bfill,
    int* __restrict__ row_start, int* __restrict__ row_end,
    int* __restrict__ src_sorted, int cap, int N)
{
    __shared__ unsigned lp[CSR_CAP];
    __shared__ int lcnt[256], loff[256], lfill[256];
    __shared__ int ws[4];
    const int tid = threadIdx.x;
    const int b = blockIdx.x;
    const int beg = b * cap;
    const int len = bfill[b];

    lcnt[tid] = 0;
    __syncthreads();
    for (int p = tid; p < len; p += 256) {
        unsigned u = staging[beg + p];
        if (p < CSR_CAP) lp[p] = u;
        atomicAdd(&lcnt[(u >> 16) & 255], 1);
    }
    __syncthreads();
    {
        int lane = tid & 63, wid = tid >> 6;
        int v = lcnt[tid];
        int incl = wave_iscan(v, lane);
        if (lane == 63) ws[wid] = incl;
        __syncthreads();
        int woff = 0;
        for (int w = 0; w < wid; w++) woff += ws[w];
        int excl = woff + incl - v;
        loff[tid] = excl;
        lfill[tid] = excl;
        int node = (b << 8) + tid;
        if (node < N) { row_start[node] = beg + excl; row_end[node] = beg + excl + v; }
    }
    __syncthreads();
    for (int p = tid; p < len; p += 256) {
        unsigned u = (p < CSR_CAP) ? lp[p] : staging[beg + p];
        int pos = atomicAdd(&lfill[(u >> 16) & 255], 1);
        src_sorted[beg + pos] = (int)(u & 0xFFFFu);
    }
}

// ---------------------------------------------------------------------------
// Fused per-destination aggregation: fp16 gather 16 B/lane, 4-stream edge
// unroll with index prefetch. Output fp16 (inter-layer) or fp32 (final).
// ---------------------------------------------------------------------------
template <int F, bool RELU, typename OT>
__global__ __launch_bounds__(256) void gat_aggregate(
    const int* __restrict__ row_start, const int* __restrict__ row_end,
    const int* __restrict__ src_sorted, const __half* __restrict__ hh,
    const float* __restrict__ aS, const float* __restrict__ aD,
    const float* __restrict__ bias, OT* __restrict__ out, int N)
{
    constexpr int LPE = F / 8;          // lanes per edge (16 or 8)
    constexpr int EPW = 64 / LPE;       // edge slots per wave (4 or 8)

    const int i = blockIdx.x * 4 + (threadIdx.x >> 6);
    if (i >= N) return;
    const int lane = threadIdx.x & 63;
    const int sub = lane / LPE;
    const int l = lane % LPE;

    const float adi = aD[i];
    const int start = row_start[i];
    const int end = row_end[i];

    float accA[8], accB[8];
#pragma unroll
    for (int q = 0; q < 8; q++) { accA[q] = 0.f; accB[q] = 0.f; }
    float denA = 0.f, denB = 0.f;

    int e = start + sub;
    int s0 = (e + 0 * EPW < end) ? src_sorted[e + 0 * EPW] : -1;
    int s1 = (e + 1 * EPW < end) ? src_sorted[e + 1 * EPW] : -1;
    int s2 = (e + 2 * EPW < end) ? src_sorted[e + 2 * EPW] : -1;
    int s3 = (e + 3 * EPW < end) ? src_sorted[e + 3 * EPW] : -1;

    while (s0 >= 0) {
        int eb = e + 4 * EPW;
        int n0 = (eb + 0 * EPW < end) ? src_sorted[eb + 0 * EPW] : -1;
        int n1 = (eb + 1 * EPW < end) ? src_sorted[eb + 1 * EPW] : -1;
        int n2 = (eb + 2 * EPW < end) ? src_sorted[eb + 2 * EPW] : -1;
        int n3 = (eb + 3 * EPW < end) ? src_sorted[eb + 3 * EPW] : -1;

        {
            float w = __expf(leaky(aS[s0] + adi));
            uint4 u = *(const uint4*)(hh + (size_t)s0 * F + l * 8);
            const __half2* hp = (const __half2*)&u;
#pragma unroll
            for (int q = 0; q < 4; q++) {
                float2 f = __half22float2(hp[q]);
                accA[q * 2] += w * f.x; accA[q * 2 + 1] += w * f.y;
            }
            denA += w;
        }
        if (s1 >= 0) {
            float w = __expf(leaky(aS[s1] + adi));
            uint4 u = *(const uint4*)(hh + (size_t)s1 * F + l * 8);
            const __half2* hp = (const __half2*)&u;
#pragma unroll
            for (int q = 0; q < 4; q++) {
                float2 f = __half22float2(hp[q]);
                accB[q * 2] += w * f.x; accB[q * 2 + 1] += w * f.y;
            }
            denB += w;
        }
        if (s2 >= 0) {
            float w = __expf(leaky(aS[s2] + adi));
            uint4 u = *(const uint4*)(hh + (size_t)s2 * F + l * 8);
            const __half2* hp = (const __half2*)&u;
#pragma unroll
            for (int q = 0; q < 4; q++) {
                float2 f = __half22float2(hp[q]);
                accA[q * 2] += w * f.x; accA[q * 2 + 1] += w * f.y;
            }
            denA += w;
        }
        if (s3 >= 0) {
            float w = __expf(leaky(aS[s3] + adi));
            uint4 u = *(const uint4*)(hh + (size_t)s3 * F + l * 8);
            const __half2* hp = (const __half2*)&u;
#pragma unroll
            for (int q = 0; q < 4; q++) {
                float2 f = __half22float2(hp[q]);
                accB[q * 2] += w * f.x; accB[q * 2 + 1] += w * f.y;
            }
            denB += w;
        }
        e = eb;
        s0 = n0; s1 = n1; s2 = n2; s3 = n3;
    }

    float acc[8];
#pragma unroll
    for (int q = 0; q < 8; q++) acc[q] = accA[q] + accB[q];
    float denom = denA + denB;

#pragma unroll
    for (int off = 32; off >= LPE; off >>= 1) {
#pragma unroll
        for (int q = 0; q < 8; q++) acc[q] += __shfl_down(acc[q], off);
        denom += __shfl_down(denom, off);
    }

    if (sub == 0) {
        float wsf = __expf(leaky(aS[i] + adi));
        uint4 u = *(const uint4*)(hh + (size_t)i * F + l * 8);
        const __half2* hp = (const __half2*)&u;
        float inv = 1.f / (denom + wsf);
        float4 b0 = *(const float4*)(bias + l * 8);
        float4 b1 = *(const float4*)(bias + l * 8 + 4);
        float o[8];
#pragma unroll
        for (int q = 0; q < 4; q++) {
            float2 f = __half22float2(hp[q]);
            o[q * 2]     = (acc[q * 2]     + wsf * f.x) * inv;
            o[q * 2 + 1] = (acc[q * 2 + 1] + wsf * f.y) * inv;
        }
        o[0] += b0.x; o[1] += b0.y; o[2] += b0.z; o[3] += b0.w;
        o[4] += b1.x; o[5] += b1.y; o[6] += b1.z; o[7] += b1.w;
        if (RELU) {
#pragma unroll
            for (int q = 0; q < 8; q++) o[q] = fmaxf(o[q], 0.f);
        }
        if constexpr (sizeof(OT) == 2) {
            __half2 qh[4];
            qh[0] = __floats2half2_rn(o[0], o[1]);
            qh[1] = __floats2half2_rn(o[2], o[3]);
            qh[2] = __floats2half2_rn(o[4], o[5]);
            qh[3] = __floats2half2_rn(o[6], o[7]);
            *(uint4*)((__half*)out + (size_t)i * F + l * 8) = *(uint4*)qh;
        } else {
            *(float4*)((float*)out + (size_t)i * F + l * 8)     = make_float4(o[0], o[1], o[2], o[3]);
            *(float4*)((float*)out + (size_t)i * F + l * 8 + 4) = make_float4(o[4], o[5], o[6], o[7]);
        }
    }
}

extern "C" void kernel_launch(void* const* d_in, const int* in_sizes, int n_in,
                              void* d_out, int out_size, void* d_ws, size_t ws_size,
                              hipStream_t stream)
{
    const float* x   = (const float*)d_in[0];
    const int*   ei  = (const int*)d_in[1];
    const float* W1  = (const float*)d_in[2];
    const float* aS1 = (const float*)d_in[3];
    const float* aD1 = (const float*)d_in[4];
    const float* b1  = (const float*)d_in[5];
    const float* W2  = (const float*)d_in[6];
    const float* aS2 = (const float*)d_in[7];
    const float* aD2 = (const float*)d_in[8];
    const float* b2  = (const float*)d_in[9];

    const int K = 128, F1 = 128, F2 = 64;
    const int N = in_sizes[0] / K;   // 50000 (< 65536: packed u32 staging valid)
    const int E = in_sizes[1] / 2;
    const int* src = ei;
    const int* dst = ei + E;

    const int Np = (N + 4) & ~3;
    const int NB = (N + 255) >> 8;
    const int nbt = (E + TILE - 1) / TILE;
    int cap = (((E / NB) * 3) / 2 + 255) & ~255;   // 1.5x mean, 256-aligned
    if (cap > CSR_CAP) cap = CSR_CAP;

    char* wsb = (char*)d_ws;
    int* bfill        = (int*)wsb;      wsb += 256 * 4;                       // zeroed
    int* row_start    = (int*)wsb;      wsb += (size_t)Np * 4;
    int* row_end      = (int*)wsb;      wsb += (size_t)Np * 4;
    unsigned* staging = (unsigned*)wsb; wsb += (size_t)NB * CSR_CAP * 4;
    int* src_sorted   = (int*)wsb;      wsb += (size_t)NB * CSR_CAP * 4;
    _Float16* hh1     = (_Float16*)wsb; wsb += (size_t)N * F1 * 2;
    _Float16* x2h     = (_Float16*)wsb; wsb += (size_t)N * F1 * 2;
    _Float16* hh2     = (_Float16*)wsb; wsb += (size_t)N * F2 * 2;
    float* as_        = (float*)wsb;    wsb += (size_t)Np * 4;
    float* ad_        = (float*)wsb;    wsb += (size_t)Np * 4;

    hipMemsetAsync(bfill, 0, 256 * 4, stream);

    dim3 blk(256);

    // ---- layer-1 GEMM (MFMA) ----
    gemm_mfma<F1, float><<<dim3((N + 63) / 64), blk, 0, stream>>>(
        x, W1, aS1, aD1, hh1, as_, ad_, N);

    // ---- CSR build (2 kernels, fixed-cap buckets, gapped CSR) ----
    bucket_scatter<<<dim3(nbt), blk, 0, stream>>>(src, dst, bfill, staging, cap, E);
    bucket_to_csr<<<dim3(NB), blk, 0, stream>>>(staging, bfill, row_start, row_end,
                                                src_sorted, cap, N);

    // ---- layer-1 aggregate -> fp16 x2 ----
    gat_aggregate<F1, true, __half><<<dim3((N + 3) / 4), blk, 0, stream>>>(
        row_start, row_end, src_sorted, (const __half*)hh1, as_, ad_, b1,
        (__half*)x2h, N);

    // ---- layer-2 GEMM (MFMA, fp16 input) ----
    gemm_mfma<F2, _Float16><<<dim3((N + 63) / 64), blk, 0, stream>>>(
        x2h, W2, aS2, aD2, hh2, as_, ad_, N);

    // ---- layer-2 aggregate -> d_out ----
    gat_aggregate<F2, false, float><<<dim3((N + 3) / 4), blk, 0, stream>>>(
        row_start, row_end, src_sorted, (const __half*)hh2, as_, ad_, b2,
        (float*)d_out, N);
}

// Round 13
// 197.152 us; speedup vs baseline: 1.4409x; 1.0131x over previous
//
#include <hip/hip_runtime.h>
#include <hip/hip_fp16.h>
#include <cstddef>

#define NEG_SLOPE 0.2f
#define TILE 4096
#define CSR_CAP 6144   // fixed per-bucket capacity; mean ~4096, sigma ~64

typedef _Float16 h8 __attribute__((ext_vector_type(8)));
typedef _Float16 h4 __attribute__((ext_vector_type(4)));
typedef float f4 __attribute__((ext_vector_type(4)));

__device__ __forceinline__ float leaky(float x) { return x >= 0.f ? x : NEG_SLOPE * x; }

__device__ __forceinline__ int wave_iscan(int v, int lane) {
#pragma unroll
    for (int off = 1; off < 64; off <<= 1) {
        int t = __shfl_up(v, off);
        if (lane >= off) v += t;
    }
    return v;
}

// ---------------------------------------------------------------------------
// FAT KERNEL: blocks [0, nblk_gemm) do the layer-1 MFMA GEMM (F=128);
// blocks [nblk_gemm, nblk_gemm+nbt) do bucket_scatter. LDS overlaid via union.
// ---------------------------------------------------------------------------
__global__ __launch_bounds__(256) void gemm1_scatter(
    const float* __restrict__ x, const float* __restrict__ W,
    const float* __restrict__ a_s, const float* __restrict__ a_d,
    _Float16* __restrict__ hh, float* __restrict__ alphaS, float* __restrict__ alphaD,
    int N, int nblk_gemm,
    const int* __restrict__ src, const int* __restrict__ dst,
    int* __restrict__ bfill, unsigned* __restrict__ staging, int cap, int E)
{
    constexpr int K = 128;
    constexpr int LDK = K + 8;
    constexpr int F = 128;
    constexpr int NT = F / 16;

    __shared__ union {
        struct { _Float16 As[64 * LDK]; _Float16 Wt[F * LDK]; } g;
        struct {
            int lcnt[256]; int loff[256]; int gbase[256]; int ws[4];
            unsigned pairs[TILE]; unsigned char bkt[TILE];
        } s;
    } u;

    const int tid = threadIdx.x;

    if (blockIdx.x < (unsigned)nblk_gemm) {
        // ================= GEMM path =================
        const int wave = tid >> 6;
        const int lane = tid & 63;
        const int q = lane >> 4;
        const int c = lane & 15;
        const int rowb = blockIdx.x * 64;

        for (int i = tid; i < 64 * (K / 4); i += 256) {
            int r = i >> 5, c4 = i & 31;
            int gr = rowb + r;
            float4 v = (gr < N) ? *(const float4*)(x + (size_t)gr * K + c4 * 4)
                                : make_float4(0.f, 0.f, 0.f, 0.f);
            h4 hv = { (_Float16)v.x, (_Float16)v.y, (_Float16)v.z, (_Float16)v.w };
            *(h4*)(u.g.As + r * LDK + c4 * 4) = hv;
        }
        for (int i = tid; i < K * F; i += 256) {
            int k = i / F, n = i % F;
            u.g.Wt[n * LDK + k] = (_Float16)W[i];
        }
        __syncthreads();

        f4 acc[NT];
#pragma unroll
        for (int nt = 0; nt < NT; nt++) acc[nt] = (f4)0.f;

        const _Float16* aw = u.g.As + (wave * 16 + c) * LDK + q * 8;
#pragma unroll
        for (int kt = 0; kt < 4; kt++) {
            h8 af = *(const h8*)(aw + kt * 32);
#pragma unroll
            for (int nt = 0; nt < NT; nt++) {
                h8 bf = *(const h8*)(u.g.Wt + (nt * 16 + c) * LDK + kt * 32 + q * 8);
                acc[nt] = __builtin_amdgcn_mfma_f32_16x16x32_f16(af, bf, acc[nt], 0, 0, 0);
            }
        }

        float asl[NT], adl[NT];
#pragma unroll
        for (int nt = 0; nt < NT; nt++) {
            asl[nt] = a_s[nt * 16 + c];
            adl[nt] = a_d[nt * 16 + c];
        }
        const int row0 = rowb + wave * 16 + q * 4;
#pragma unroll
        for (int r = 0; r < 4; r++) {
            int row = row0 + r;
            if (row < N) {
                float ps = 0.f, pd = 0.f;
#pragma unroll
                for (int nt = 0; nt < NT; nt++) {
                    float v = acc[nt][r];
                    hh[(size_t)row * F + nt * 16 + c] = (_Float16)v;
                    ps += v * asl[nt];
                    pd += v * adl[nt];
                }
#pragma unroll
                for (int off = 8; off >= 1; off >>= 1) {
                    ps += __shfl_down(ps, off, 16);
                    pd += __shfl_down(pd, off, 16);
                }
                if (c == 0) { alphaS[row] = ps; alphaD[row] = pd; }
            }
        }
    } else {
        // ================= bucket_scatter path =================
        const int base = (blockIdx.x - nblk_gemm) * TILE;
        const int vt = min(TILE, E - base);

        u.s.lcnt[tid] = 0;
        __syncthreads();

        int d[TILE / 256], s[TILE / 256], r[TILE / 256];
#pragma unroll
        for (int j = 0; j < TILE / 256; j++) {
            int idx = base + j * 256 + tid;
            if (idx < E) {
                d[j] = dst[idx]; s[j] = src[idx];
                r[j] = atomicAdd(&u.s.lcnt[d[j] >> 8], 1);
            } else d[j] = -1;
        }
        __syncthreads();
        {
            int lane = tid & 63, wid = tid >> 6;
            int v = u.s.lcnt[tid];
            int incl = wave_iscan(v, lane);
            if (lane == 63) u.s.ws[wid] = incl;
            __syncthreads();
            int woff = 0;
            for (int w = 0; w < wid; w++) woff += u.s.ws[w];
            u.s.loff[tid] = woff + incl - v;
        }
        __syncthreads();
        {
            int c = u.s.lcnt[tid];
            if (c > 0) u.s.gbase[tid] = tid * cap + atomicAdd(&bfill[tid], c);
        }
        __syncthreads();
#pragma unroll
        for (int j = 0; j < TILE / 256; j++) {
            if (d[j] >= 0) {
                int b = d[j] >> 8;
                int slot = u.s.loff[b] + r[j];
                u.s.pairs[slot] = ((unsigned)d[j] << 16) | (unsigned)s[j];
                u.s.bkt[slot] = (unsigned char)b;
            }
        }
        __syncthreads();
        for (int slot = tid; slot < vt; slot += 256) {
            int b = u.s.bkt[slot];
            staging[u.s.gbase[b] + (slot - u.s.loff[b])] = u.s.pairs[slot];
        }
    }
}

// ---------------------------------------------------------------------------
// MFMA GEMM + fused alpha dots (layer 2, fp16 input).
// ---------------------------------------------------------------------------
template <int F, typename IT>
__global__ __launch_bounds__(256) void gemm_mfma(
    const IT* __restrict__ x, const float* __restrict__ W,
    const float* __restrict__ a_s, const float* __restrict__ a_d,
    _Float16* __restrict__ hh, float* __restrict__ alphaS, float* __restrict__ alphaD,
    int N)
{
    constexpr int K = 128;
    constexpr int LDK = K + 8;
    constexpr int NT = F / 16;

    __shared__ _Float16 As[64 * LDK];
    __shared__ _Float16 Wt[F * LDK];

    const int tid = threadIdx.x;
    const int wave = tid >> 6;
    const int lane = tid & 63;
    const int q = lane >> 4;
    const int c = lane & 15;
    const int rowb = blockIdx.x * 64;

    if constexpr (sizeof(IT) == 4) {
        for (int i = tid; i < 64 * (K / 4); i += 256) {
            int r = i >> 5, c4 = i & 31;
            int gr = rowb + r;
            float4 v = (gr < N) ? *(const float4*)((const float*)x + (size_t)gr * K + c4 * 4)
                                : make_float4(0.f, 0.f, 0.f, 0.f);
            h4 hv = { (_Float16)v.x, (_Float16)v.y, (_Float16)v.z, (_Float16)v.w };
            *(h4*)(As + r * LDK + c4 * 4) = hv;
        }
    } else {
        for (int i = tid; i < 64 * (K / 8); i += 256) {
            int r = i >> 4, c8 = i & 15;
            int gr = rowb + r;
            h8 v;
            if (gr < N) v = *(const h8*)((const _Float16*)x + (size_t)gr * K + c8 * 8);
            else        v = (h8)(_Float16)0.f;
            *(h8*)(As + r * LDK + c8 * 8) = v;
        }
    }
    for (int i = tid; i < K * F; i += 256) {
        int k = i / F, n = i % F;
        Wt[n * LDK + k] = (_Float16)W[i];
    }
    __syncthreads();

    f4 acc[NT];
#pragma unroll
    for (int nt = 0; nt < NT; nt++) acc[nt] = (f4)0.f;

    const _Float16* aw = As + (wave * 16 + c) * LDK + q * 8;
#pragma unroll
    for (int kt = 0; kt < 4; kt++) {
        h8 af = *(const h8*)(aw + kt * 32);
#pragma unroll
        for (int nt = 0; nt < NT; nt++) {
            h8 bf = *(const h8*)(Wt + (nt * 16 + c) * LDK + kt * 32 + q * 8);
            acc[nt] = __builtin_amdgcn_mfma_f32_16x16x32_f16(af, bf, acc[nt], 0, 0, 0);
        }
    }

    float asl[NT], adl[NT];
#pragma unroll
    for (int nt = 0; nt < NT; nt++) {
        asl[nt] = a_s[nt * 16 + c];
        adl[nt] = a_d[nt * 16 + c];
    }
    const int row0 = rowb + wave * 16 + q * 4;
#pragma unroll
    for (int r = 0; r < 4; r++) {
        int row = row0 + r;
        if (row < N) {
            float ps = 0.f, pd = 0.f;
#pragma unroll
            for (int nt = 0; nt < NT; nt++) {
                float v = acc[nt][r];
                hh[(size_t)row * F + nt * 16 + c] = (_Float16)v;
                ps += v * asl[nt];
                pd += v * adl[nt];
            }
#pragma unroll
            for (int off = 8; off >= 1; off >>= 1) {
                ps += __shfl_down(ps, off, 16);
                pd += __shfl_down(pd, off, 16);
            }
            if (c == 0) { alphaS[row] = ps; alphaD[row] = pd; }
        }
    }
}

// ---------------------------------------------------------------------------
// bucket_to_csr: per bucket, node-level counts/scan -> gapped CSR
// (row_start/row_end) + grouped src_sorted.
// ---------------------------------------------------------------------------
__global__ __launch_bounds__(256) void bucket_to_csr(
    const unsigned* __restrict__ staging, const int* __restrict__ bfill,
    int* __restrict__ row_start, int* __restrict__ row_end,
    int* __restrict__ src_sorted, int cap, int N)
{
    __shared__ unsigned lp[CSR_CAP];
    __shared__ int lcnt[256], loff[256], lfill[256];
    __shared__ int ws[4];
    const int tid = threadIdx.x;
    const int b = blockIdx.x;
    const int beg = b * cap;
    const int len = bfill[b];

    lcnt[tid] = 0;
    __syncthreads();
    for (int p = tid; p < len; p += 256) {
        unsigned u = staging[beg + p];
        if (p < CSR_CAP) lp[p] = u;
        atomicAdd(&lcnt[(u >> 16) & 255], 1);
    }
    __syncthreads();
    {
        int lane = tid & 63, wid = tid >> 6;
        int v = lcnt[tid];
        int incl = wave_iscan(v, lane);
        if (lane == 63) ws[wid] = incl;
        __syncthreads();
        int woff = 0;
        for (int w = 0; w < wid; w++) woff += ws[w];
        int excl = woff + incl - v;
        loff[tid] = excl;
        lfill[tid] = excl;
        int node = (b << 8) + tid;
        if (node < N) { row_start[node] = beg + excl; row_end[node] = beg + excl + v; }
    }
    __syncthreads();
    for (int p = tid; p < len; p += 256) {
        unsigned u = (p < CSR_CAP) ? lp[p] : staging[beg + p];
        int pos = atomicAdd(&lfill[(u >> 16) & 255], 1);
        src_sorted[beg + pos] = (int)(u & 0xFFFFu);
    }
}

// ---------------------------------------------------------------------------
// Fused per-destination aggregation: fp16 gather 16 B/lane, 4-stream edge
// unroll with index prefetch. Output fp16 (inter-layer) or fp32 (final).
// ---------------------------------------------------------------------------
template <int F, bool RELU, typename OT>
__global__ __launch_bounds__(256) void gat_aggregate(
    const int* __restrict__ row_start, const int* __restrict__ row_end,
    const int* __restrict__ src_sorted, const __half* __restrict__ hh,
    const float* __restrict__ aS, const float* __restrict__ aD,
    const float* __restrict__ bias, OT* __restrict__ out, int N)
{
    constexpr int LPE = F / 8;          // lanes per edge (16 or 8)
    constexpr int EPW = 64 / LPE;       // edge slots per wave (4 or 8)

    const int i = blockIdx.x * 4 + (threadIdx.x >> 6);
    if (i >= N) return;
    const int lane = threadIdx.x & 63;
    const int sub = lane / LPE;
    const int l = lane % LPE;

    const float adi = aD[i];
    const int start = row_start[i];
    const int end = row_end[i];

    float accA[8], accB[8];
#pragma unroll
    for (int q = 0; q < 8; q++) { accA[q] = 0.f; accB[q] = 0.f; }
    float denA = 0.f, denB = 0.f;

    int e = start + sub;
    int s0 = (e + 0 * EPW < end) ? src_sorted[e + 0 * EPW] : -1;
    int s1 = (e + 1 * EPW < end) ? src_sorted[e + 1 * EPW] : -1;
    int s2 = (e + 2 * EPW < end) ? src_sorted[e + 2 * EPW] : -1;
    int s3 = (e + 3 * EPW < end) ? src_sorted[e + 3 * EPW] : -1;

    while (s0 >= 0) {
        int eb = e + 4 * EPW;
        int n0 = (eb + 0 * EPW < end) ? src_sorted[eb + 0 * EPW] : -1;
        int n1 = (eb + 1 * EPW < end) ? src_sorted[eb + 1 * EPW] : -1;
        int n2 = (eb + 2 * EPW < end) ? src_sorted[eb + 2 * EPW] : -1;
        int n3 = (eb + 3 * EPW < end) ? src_sorted[eb + 3 * EPW] : -1;

        {
            float w = __expf(leaky(aS[s0] + adi));
            uint4 u = *(const uint4*)(hh + (size_t)s0 * F + l * 8);
            const __half2* hp = (const __half2*)&u;
#pragma unroll
            for (int q = 0; q < 4; q++) {
                float2 f = __half22float2(hp[q]);
                accA[q * 2] += w * f.x; accA[q * 2 + 1] += w * f.y;
            }
            denA += w;
        }
        if (s1 >= 0) {
            float w = __expf(leaky(aS[s1] + adi));
            uint4 u = *(const uint4*)(hh + (size_t)s1 * F + l * 8);
            const __half2* hp = (const __half2*)&u;
#pragma unroll
            for (int q = 0; q < 4; q++) {
                float2 f = __half22float2(hp[q]);
                accB[q * 2] += w * f.x; accB[q * 2 + 1] += w * f.y;
            }
            denB += w;
        }
        if (s2 >= 0) {
            float w = __expf(leaky(aS[s2] + adi));
            uint4 u = *(const uint4*)(hh + (size_t)s2 * F + l * 8);
            const __half2* hp = (const __half2*)&u;
#pragma unroll
            for (int q = 0; q < 4; q++) {
                float2 f = __half22float2(hp[q]);
                accA[q * 2] += w * f.x; accA[q * 2 + 1] += w * f.y;
            }
            denA += w;
        }
        if (s3 >= 0) {
            float w = __expf(leaky(aS[s3] + adi));
            uint4 u = *(const uint4*)(hh + (size_t)s3 * F + l * 8);
            const __half2* hp = (const __half2*)&u;
#pragma unroll
            for (int q = 0; q < 4; q++) {
                float2 f = __half22float2(hp[q]);
                accB[q * 2] += w * f.x; accB[q * 2 + 1] += w * f.y;
            }
            denB += w;
        }
        e = eb;
        s0 = n0; s1 = n1; s2 = n2; s3 = n3;
    }

    float acc[8];
#pragma unroll
    for (int q = 0; q < 8; q++) acc[q] = accA[q] + accB[q];
    float denom = denA + denB;

#pragma unroll
    for (int off = 32; off >= LPE; off >>= 1) {
#pragma unroll
        for (int q = 0; q < 8; q++) acc[q] += __shfl_down(acc[q], off);
        denom += __shfl_down(denom, off);
    }

    if (sub == 0) {
        float wsf = __expf(leaky(aS[i] + adi));
        uint4 u = *(const uint4*)(hh + (size_t)i * F + l * 8);
        const __half2* hp = (const __half2*)&u;
        float inv = 1.f / (denom + wsf);
        float4 b0 = *(const float4*)(bias + l * 8);
        float4 b1 = *(const float4*)(bias + l * 8 + 4);
        float o[8];
#pragma unroll
        for (int q = 0; q < 4; q++) {
            float2 f = __half22float2(hp[q]);
            o[q * 2]     = (acc[q * 2]     + wsf * f.x) * inv;
            o[q * 2 + 1] = (acc[q * 2 + 1] + wsf * f.y) * inv;
        }
        o[0] += b0.x; o[1] += b0.y; o[2] += b0.z; o[3] += b0.w;
        o[4] += b1.x; o[5] += b1.y; o[6] += b1.z; o[7] += b1.w;
        if (RELU) {
#pragma unroll
            for (int q = 0; q < 8; q++) o[q] = fmaxf(o[q], 0.f);
        }
        if constexpr (sizeof(OT) == 2) {
            __half2 qh[4];
            qh[0] = __floats2half2_rn(o[0], o[1]);
            qh[1] = __floats2half2_rn(o[2], o[3]);
            qh[2] = __floats2half2_rn(o[4], o[5]);
            qh[3] = __floats2half2_rn(o[6], o[7]);
            *(uint4*)((__half*)out + (size_t)i * F + l * 8) = *(uint4*)qh;
        } else {
            *(float4*)((float*)out + (size_t)i * F + l * 8)     = make_float4(o[0], o[1], o[2], o[3]);
            *(float4*)((float*)out + (size_t)i * F + l * 8 + 4) = make_float4(o[4], o[5], o[6], o[7]);
        }
    }
}

extern "C" void kernel_launch(void* const* d_in, const int* in_sizes, int n_in,
                              void* d_out, int out_size, void* d_ws, size_t ws_size,
                              hipStream_t stream)
{
    const float* x   = (const float*)d_in[0];
    const int*   ei  = (const int*)d_in[1];
    const float* W1  = (const float*)d_in[2];
    const float* aS1 = (const float*)d_in[3];
    const float* aD1 = (const float*)d_in[4];
    const float* b1  = (const float*)d_in[5];
    const float* W2  = (const float*)d_in[6];
    const float* aS2 = (const float*)d_in[7];
    const float* aD2 = (const float*)d_in[8];
    const float* b2  = (const float*)d_in[9];

    const int K = 128, F1 = 128, F2 = 64;
    const int N = in_sizes[0] / K;   // 50000 (< 65536: packed u32 staging valid)
    const int E = in_sizes[1] / 2;
    const int* src = ei;
    const int* dst = ei + E;

    const int Np = (N + 4) & ~3;
    const int NB = (N + 255) >> 8;
    const int nbt = (E + TILE - 1) / TILE;
    const int nblk_gemm = (N + 63) / 64;
    int cap = (((E / NB) * 3) / 2 + 255) & ~255;   // 1.5x mean, 256-aligned
    if (cap > CSR_CAP) cap = CSR_CAP;

    char* wsb = (char*)d_ws;
    int* bfill        = (int*)wsb;      wsb += 256 * 4;                       // zeroed
    int* row_start    = (int*)wsb;      wsb += (size_t)Np * 4;
    int* row_end      = (int*)wsb;      wsb += (size_t)Np * 4;
    unsigned* staging = (unsigned*)wsb; wsb += (size_t)NB * CSR_CAP * 4;
    int* src_sorted   = (int*)wsb;      wsb += (size_t)NB * CSR_CAP * 4;
    _Float16* hh1     = (_Float16*)wsb; wsb += (size_t)N * F1 * 2;
    _Float16* x2h     = (_Float16*)wsb; wsb += (size_t)N * F1 * 2;
    _Float16* hh2     = (_Float16*)wsb; wsb += (size_t)N * F2 * 2;
    float* as_        = (float*)wsb;    wsb += (size_t)Np * 4;
    float* ad_        = (float*)wsb;    wsb += (size_t)Np * 4;

    hipMemsetAsync(bfill, 0, 256 * 4, stream);

    dim3 blk(256);

    // ---- layer-1 GEMM (MFMA) overlapped with bucket_scatter ----
    gemm1_scatter<<<dim3(nblk_gemm + nbt), blk, 0, stream>>>(
        x, W1, aS1, aD1, hh1, as_, ad_, N, nblk_gemm,
        src, dst, bfill, staging, cap, E);

    // ---- CSR finalize ----
    bucket_to_csr<<<dim3(NB), blk, 0, stream>>>(staging, bfill, row_start, row_end,
                                                src_sorted, cap, N);

    // ---- layer-1 aggregate -> fp16 x2 ----
    gat_aggregate<F1, true, __half><<<dim3((N + 3) / 4), blk, 0, stream>>>(
        row_start, row_end, src_sorted, (const __half*)hh1, as_, ad_, b1,
        (__half*)x2h, N);

    // ---- layer-2 GEMM (MFMA, fp16 input) ----
    gemm_mfma<F2, _Float16><<<dim3((N + 63) / 64), blk, 0, stream>>>(
        x2h, W2, aS2, aD2, hh2, as_, ad_, N);

    // ---- layer-2 aggregate -> d_out ----
    gat_aggregate<F2, false, float><<<dim3((N + 3) / 4), blk, 0, stream>>>(
        row_start, row_end, src_sorted, (const __half*)hh2, as_, ad_, b2,
        (float*)d_out, N);
}